// Round 4
// baseline (247.755 us; speedup 1.0000x reference)
//
#include <hip/hip_runtime.h>

// MultiQueryAttention with kv_len == 1: softmax over a singleton axis is
// identically 1, so the output is independent of query/Wq/key/Wk.
//   V[b,d]      = value[b,:]·Wv[:,d] + bv[d]                      (8 x 64)
//   out_vec[b,j]= sum_c V[b, c&63] * Wo[c,j] + bo[j]              (8 x 1024)
//   out[b,s,:]  = out_vec[b,:]  for all s                         (8 x 4096 x 1024)
//
// Single fused kernel: grid = 8 b x 16 j-slices x 2 s-halves = 256 blocks
// (1 per CU). Each block:
//   phase 1: recompute V[b] (Wv 256 KB, L2-hot; redundancy ~2 MB HBM total)
//   phase 2: out_vec slice [jbase, jbase+64) (Wo slice 256 KB, L2-shared
//            across the 16 blocks with the same jc)
//   phase 3: NT-stream 2048 rows x 256 B to d_out (write-BW bound, ~20 us
//            floor chip-wide)

#define D_MODEL 1024
#define HEAD_DIM 64
#define B_SIZE 8
#define S_LEN 4096

typedef float vfloat4 __attribute__((ext_vector_type(4)));

__global__ __launch_bounds__(256) void k_fused(
    const float* __restrict__ value, const float4* __restrict__ Wv4,
    const float4* __restrict__ bv4, const float* __restrict__ Wo,
    const float* __restrict__ bo, vfloat4* __restrict__ out4) {
  int bx = blockIdx.x;
  int b = bx >> 5;          // 0..7
  int jc = (bx >> 1) & 15;  // 0..15
  int sh = bx & 1;          // s-half
  int jbase = jc * 64;
  int t = threadIdx.x;

  __shared__ __align__(16) float Vsh[64];
  __shared__ float4 red[16][16];
  __shared__ float red2[4][64];
  __shared__ __align__(16) float outSh[64];

  // --- Phase 1: V[b,:] = value[b,:]·Wv + bv ---
  {
    int d4 = t & 15;  // float4 column (64 floats = 16 float4)
    int kp = t >> 4;  // 0..15, 64 k each
    const float* vrow = value + b * D_MODEL;
    float4 acc = make_float4(0.f, 0.f, 0.f, 0.f);
    int k0 = kp * 64;
#pragma unroll 8
    for (int i = 0; i < 64; ++i) {
      int k = k0 + i;
      float v = vrow[k];            // 16 lanes share address -> L1 broadcast
      float4 w = Wv4[k * 16 + d4];  // 256B coalesced segment per 16 lanes
      acc.x += v * w.x;
      acc.y += v * w.y;
      acc.z += v * w.z;
      acc.w += v * w.w;
    }
    red[kp][d4] = acc;
    __syncthreads();
    if (t < 16) {
      float4 s = bv4[t];
#pragma unroll
      for (int p = 0; p < 16; ++p) {
        float4 r = red[p][t];
        s.x += r.x;
        s.y += r.y;
        s.z += r.z;
        s.w += r.w;
      }
      ((float4*)Vsh)[t] = s;
    }
    __syncthreads();
  }

  // --- Phase 2: outSh[j] = sum_c Vsh[c&63] * Wo[c, jbase+j] + bo[jbase+j] ---
  {
    int j = t & 63;
    int part = t >> 6;  // 0..3, 256 c each (wave-uniform)
    float acc = 0.f;
    int c0 = part * 256;
#pragma unroll 8
    for (int i = 0; i < 256; ++i) {
      int c = c0 + i;
      // Vsh index wave-uniform -> LDS broadcast; Wo read 256B coalesced.
      acc += Vsh[c & 63] * Wo[c * D_MODEL + jbase + j];
    }
    red2[part][j] = acc;
    __syncthreads();
    if (t < 64) {
      outSh[t] =
          red2[0][t] + red2[1][t] + red2[2][t] + red2[3][t] + bo[jbase + t];
    }
    __syncthreads();
  }

  // --- Phase 3: broadcast rows [sh*2048, sh*2048+2048), cols j-slice ---
  {
    int lane4 = t & 15;  // float4 col within slice (16 x 16B = 256B)
    int r = t >> 4;      // 16 rows in parallel
    vfloat4 v = ((const vfloat4*)outSh)[lane4];
    size_t s0 = (size_t)sh * 2048 + r;
    vfloat4* p = out4 + ((size_t)b * S_LEN + s0) * 256 + jc * 16 + lane4;
#pragma unroll 8
    for (int i = 0; i < 128; ++i) {
      __builtin_nontemporal_store(v, p);
      p += 16 * 256;  // 16 rows ahead
    }
  }
}

extern "C" void kernel_launch(void* const* d_in, const int* in_sizes, int n_in,
                              void* d_out, int out_size, void* d_ws,
                              size_t ws_size, hipStream_t stream) {
  // setup_inputs order: query(0) key(1) value(2) Wq(3) bq(4) Wk(5) bk(6)
  //                     Wv(7) bv(8) Wo(9) bo(10)
  const float* value = (const float*)d_in[2];
  const float* Wv = (const float*)d_in[7];
  const float* bv = (const float*)d_in[8];
  const float* Wo = (const float*)d_in[9];
  const float* bo = (const float*)d_in[10];

  k_fused<<<B_SIZE * 16 * 2, 256, 0, stream>>>(value, (const float4*)Wv,
                                               (const float4*)bv, Wo, bo,
                                               (vfloat4*)d_out);
}

// Round 5
// 243.629 us; speedup vs baseline: 1.0169x; 1.0169x over previous
//
#include <hip/hip_runtime.h>

// MultiQueryAttention with kv_len == 1: softmax over a singleton axis is
// identically 1, so the output is independent of query/Wq/key/Wk.
//   V[b,d]      = value[b,:]·Wv[:,d] + bv[d]                      (8 x 64)
//   out_vec[b,j]= sum_c V[b, c&63] * Wo[c,j] + bo[j]              (8 x 1024)
//   out[b,s,:]  = out_vec[b,:]  for all s                         (8 x 4096 x 1024)
//
// Best-measured structure (round 3): 2 kernels.
//  A) k_outvec: 128 blocks (8 b x 16 j-slices of 64). Each block redundantly
//     recomputes V[b] (Wv is 256 KB, L2-hot).
//  B) k_broadcast: pure write-BW kernel, NT stores, 4 KB contiguous per
//     block-iteration. 134 MB / ~6.8 TB/s ≈ 20 us floor.
// Fused 1-kernel variant measured WORSE (247.8 vs 243.6): no co-resident
// waves to overlap phase transitions at 1 block/CU, and 256B store segments
// lose burst efficiency vs 4KB rows.

#define D_MODEL 1024
#define HEAD_DIM 64
#define B_SIZE 8
#define S_LEN 4096

typedef float vfloat4 __attribute__((ext_vector_type(4)));

__global__ __launch_bounds__(256) void k_outvec(
    const float* __restrict__ value, const float4* __restrict__ Wv4,
    const float4* __restrict__ bv4, const float* __restrict__ Wo,
    const float* __restrict__ bo, float* __restrict__ outv) {
  int b = blockIdx.x >> 4;   // 0..7
  int jc = blockIdx.x & 15;  // 0..15
  int jbase = jc * 64;
  int t = threadIdx.x;

  // --- V[b,:] = value[b,:]·Wv + bv ---
  __shared__ __align__(16) float Vsh[64];
  {
    int d4 = t & 15;  // float4 column (64 floats = 16 float4)
    int kp = t >> 4;  // 0..15, 64 k each
    const float* vrow = value + b * D_MODEL;
    float4 acc = make_float4(0.f, 0.f, 0.f, 0.f);
    int k0 = kp * 64;
#pragma unroll 8
    for (int i = 0; i < 64; ++i) {
      int k = k0 + i;
      float v = vrow[k];            // 16 lanes share address -> L1 broadcast
      float4 w = Wv4[k * 16 + d4];  // 256B coalesced segment per 16 lanes
      acc.x += v * w.x;
      acc.y += v * w.y;
      acc.z += v * w.z;
      acc.w += v * w.w;
    }
    __shared__ float4 red[16][16];
    red[kp][d4] = acc;
    __syncthreads();
    if (t < 16) {
      float4 s = bv4[t];
#pragma unroll
      for (int p = 0; p < 16; ++p) {
        float4 r = red[p][t];
        s.x += r.x;
        s.y += r.y;
        s.z += r.z;
        s.w += r.w;
      }
      ((float4*)Vsh)[t] = s;
    }
    __syncthreads();
  }

  // --- out_vec slice: j in [jbase, jbase+64) ---
  int j = t & 63;
  int part = t >> 6;  // 0..3, 256 c each (wave-uniform)
  float acc = 0.f;
  int c0 = part * 256;
#pragma unroll 8
  for (int i = 0; i < 256; ++i) {
    int c = c0 + i;
    // Vsh index wave-uniform -> LDS broadcast; Wo read 256B coalesced.
    acc += Vsh[c & 63] * Wo[c * D_MODEL + jbase + j];
  }
  __shared__ float red2[4][64];
  red2[part][j] = acc;
  __syncthreads();
  if (t < 64) {
    outv[b * D_MODEL + jbase + t] =
        red2[0][t] + red2[1][t] + red2[2][t] + red2[3][t] + bo[jbase + t];
  }
}

// Pure write-BW broadcast. grid = 8 b x 128 row-groups. Each block-iteration
// writes one contiguous 4 KB row; NT stores keep L2 clean.
__global__ __launch_bounds__(256) void k_broadcast(
    const vfloat4* __restrict__ vec4, vfloat4* __restrict__ out4) {
  int b = blockIdx.x >> 7;
  int g = blockIdx.x & 127;
  int t = threadIdx.x;  // 256 vfloat4 lanes cover D_MODEL
  vfloat4 v = vec4[b * 256 + t];
  vfloat4* p = out4 + (size_t)b * S_LEN * 256 + (size_t)g * 256 + t;
#pragma unroll 8
  for (int i = 0; i < 32; ++i) {
    __builtin_nontemporal_store(v, p);
    p += 128 * 256;  // 128 rows ahead
  }
}

extern "C" void kernel_launch(void* const* d_in, const int* in_sizes, int n_in,
                              void* d_out, int out_size, void* d_ws,
                              size_t ws_size, hipStream_t stream) {
  // setup_inputs order: query(0) key(1) value(2) Wq(3) bq(4) Wk(5) bk(6)
  //                     Wv(7) bv(8) Wo(9) bo(10)
  const float* value = (const float*)d_in[2];
  const float* Wv = (const float*)d_in[7];
  const float* bv = (const float*)d_in[8];
  const float* Wo = (const float*)d_in[9];
  const float* bo = (const float*)d_in[10];

  float* outv = (float*)d_ws;  // 8*1024 floats, 16B-aligned (harness alloc)

  k_outvec<<<B_SIZE * 16, 256, 0, stream>>>(value, (const float4*)Wv,
                                            (const float4*)bv, Wo, bo, outv);
  k_broadcast<<<B_SIZE * 128, 256, 0, stream>>>((const vfloat4*)outv,
                                                (vfloat4*)d_out);
}